// Round 5
// baseline (414.943 us; speedup 1.0000x reference)
//
#include <hip/hip_runtime.h>

// Fixed sizes
#define G_    32
#define O_    16
#define OUTD  128
#define DS_   64      // scalar half / SDIM
#define VC    48      // V*3
#define M_    2048    // rows per graph
#define ROWS  128     // rows per chunk
#define CPG   16      // chunks per graph
#define XP    136     // xT / cT pitch in bf16 elems (rows 16B-aligned: 272B)
#define XPD   68      // pitch in dwords
#define WVP   72      // wv_s pitch in bf16
#define YLP   132     // y_lds pitch in f32

typedef __attribute__((ext_vector_type(8))) short short8;
typedef __attribute__((ext_vector_type(4))) float f32x4;

__device__ __forceinline__ unsigned short f2bf(float f) {
  unsigned u = __float_as_uint(f);
  return (unsigned short)((u + 0x7FFFu + ((u >> 16) & 1u)) >> 16);
}
__device__ __forceinline__ float bf2f(short v) {
  return __uint_as_float(((unsigned)(unsigned short)v) << 16);
}

// Per-graph barrier: monotonic counter, 8 blocks/graph.
// Co-residency is forced: 107 KB LDS/block -> 1 block/CU, grid 256 = #CUs,
// so all 8 blocks of a graph are resident and the spin always resolves.
// Bounded guard converts any pathological case into a clean numeric failure.
__device__ __forceinline__ void graph_barrier(unsigned* cnt, unsigned target) {
  __threadfence();                       // make this thread's stores agent-visible
  __syncthreads();                       // all block threads' fences done
  if (threadIdx.x == 0) {
    __hip_atomic_fetch_add(cnt, 1u, __ATOMIC_RELEASE, __HIP_MEMORY_SCOPE_AGENT);
    unsigned guard = 0;
    while (__hip_atomic_load(cnt, __ATOMIC_ACQUIRE, __HIP_MEMORY_SCOPE_AGENT) < target) {
      __builtin_amdgcn_s_sleep(2);
      if (++guard > (1u << 20)) break;   // ~50ms; never trips if resident
    }
  }
  __syncthreads();
  __threadfence();                       // reader-side cache discipline
}

// ---------------------------------------------------------------------------
// Single persistent kernel. Block b: g = b>>3, pair = b&7.
//  A-role: 2 chunks (pair*2 + h), h = threadIdx.x>>8; xT stays in LDS for all
//          3 routing iterations (x read from HBM exactly once, no xTg buffer).
//  B-role: 2 capsules o = pair*2 + {0,1} (identical math to passing capsB).
//  5 per-graph barriers replace 5 kernel boundaries.
// ---------------------------------------------------------------------------
__global__ __launch_bounds__(512) void caps_mega(
    const float* __restrict__ x, const float* __restrict__ xv,
    const float* __restrict__ Ws, const float* __restrict__ Wv,
    const float* __restrict__ bias, float* __restrict__ wvacc,
    float* __restrict__ y_part, float* __restrict__ routed_part,
    float* __restrict__ ysum_part, float* __restrict__ caps,
    float* __restrict__ vecs, unsigned* __restrict__ bar)
{
  const int b = blockIdx.x, g = b >> 3, pair = b & 7;
  const int t = threadIdx.x, h = t >> 8, tt = t & 255;
  const int lane = tt & 63, w = tt >> 6;
  const int chunk = pair * 2 + h;
  const int blk_lin = g * CPG + chunk;

  __shared__ short xT[2][128 * XP];     // 69632 B, persistent
  __shared__ short cT[2][O_ * XP];      // 8704 B
  __shared__ short wv_s[O_ * WVP];      // 2304 B (shared: same g both halves)
  __shared__ float y_lds[2][16 * YLP];  // 16896 B
  __shared__ float cp_s[2][16][17];     // 2176 B
  __shared__ float xv_s[2][16 * VC];    // 6144 B
  __shared__ float yB[2][128];          // 1024 B (B-role)
  __shared__ float vB[2][64];           // 512 B
  __shared__ float pn_s[4];             // 16 B
  // total ~107.4 KB -> forces 1 block/CU (2x107 > 160 KB)

  unsigned* cnt = bar + g * 64;         // 256B-strided per-graph counter

  // ================= phase 0: stage x -> xT, xv -> LDS, colsums =============
  {
    const float* xg = x + (size_t)(g * M_ + chunk * ROWS) * OUTD;
    const int rg = tt >> 2, qc = tt & 3;
    const float4* r0q = (const float4*)(xg + (size_t)(2 * rg) * OUTD + qc * 32);
    const float4* r1q = (const float4*)(xg + (size_t)(2 * rg + 1) * OUTD + qc * 32);
    float4 a0 = r0q[0], a1 = r0q[1], a2 = r0q[2], a3 = r0q[3],
           a4 = r0q[4], a5 = r0q[5], a6 = r0q[6], a7 = r0q[7];
    float4 b0 = r1q[0], b1 = r1q[1], b2 = r1q[2], b3 = r1q[3],
           b4 = r1q[4], b5 = r1q[5], b6 = r1q[6], b7 = r1q[7];
    unsigned* xTd = (unsigned*)&xT[h][0];
    const int cb = qc * 32;
#define STAGE4(S, A, B)                                                        \
    xTd[(cb + S*4 + 0) * XPD + rg] = (unsigned)f2bf(A.x) | ((unsigned)f2bf(B.x) << 16); \
    xTd[(cb + S*4 + 1) * XPD + rg] = (unsigned)f2bf(A.y) | ((unsigned)f2bf(B.y) << 16); \
    xTd[(cb + S*4 + 2) * XPD + rg] = (unsigned)f2bf(A.z) | ((unsigned)f2bf(B.z) << 16); \
    xTd[(cb + S*4 + 3) * XPD + rg] = (unsigned)f2bf(A.w) | ((unsigned)f2bf(B.w) << 16);
    STAGE4(0, a0, b0) STAGE4(1, a1, b1) STAGE4(2, a2, b2) STAGE4(3, a3, b3)
    STAGE4(4, a4, b4) STAGE4(5, a5, b5) STAGE4(6, a6, b6) STAGE4(7, a7, b7)
#undef STAGE4
  }
  {
    const float* xvg = xv + (size_t)(g * 256 + chunk * 16) * VC;
    for (int i = tt; i < 16 * VC; i += 256) xv_s[h][i] = xvg[i];
  }
  __syncthreads();
  {
    const int k = tt >> 1, half = tt & 1;
    float s = 0.f;
#pragma unroll
    for (int j = 0; j < 8; ++j) {
      short8 v = *(const short8*)&xT[h][k * XP + half * 64 + j * 8];
#pragma unroll
      for (int e = 0; e < 8; ++e) s += bf2f(v[e]);
    }
    s += __shfl_xor(s, 1);
    if (half == 0) ysum_part[(size_t)blk_lin * 128 + k] = s;
  }
  graph_barrier(cnt, 8);

  // ---- role macros ---------------------------------------------------------
#define LOGIT_TILE(NT2, CF)                                                    \
    {                                                                          \
      const int nt = 2 * w + NT2;                                              \
      const int mcol = nt * 16 + mrow;                                         \
      f32x4 acc = {0.f, 0.f, 0.f, 0.f};                                        \
      _Pragma("unroll")                                                        \
      for (int ks = 0; ks < 2; ++ks) {                                         \
        short8 af = *(const short8*)&wv_s[mrow * WVP + ks * 32 + gq * 8];      \
        short8 bfr;                                                            \
        _Pragma("unroll")                                                      \
        for (int e = 0; e < 8; ++e)                                            \
          bfr[e] = xT[h][(ks * 32 + gq * 8 + e) * XP + mcol];                  \
        acc = __builtin_amdgcn_mfma_f32_16x16x32_bf16(af, bfr, acc, 0, 0, 0);  \
      }                                                                        \
      float mx = fmaxf(fmaxf(acc[0], acc[1]), fmaxf(acc[2], acc[3]));          \
      mx = fmaxf(mx, __shfl_xor(mx, 16));                                      \
      mx = fmaxf(mx, __shfl_xor(mx, 32));                                      \
      float e0 = __expf(acc[0] - mx), e1 = __expf(acc[1] - mx);                \
      float e2 = __expf(acc[2] - mx), e3 = __expf(acc[3] - mx);                \
      float sm = e0 + e1 + e2 + e3;                                            \
      sm += __shfl_xor(sm, 16);                                                \
      sm += __shfl_xor(sm, 32);                                                \
      float inv = 1.f / sm;                                                    \
      CF[0] = e0 * inv; CF[1] = e1 * inv; CF[2] = e2 * inv; CF[3] = e3 * inv;  \
      cT[h][(gq * 4 + 0) * XP + mcol] = (short)f2bf(CF[0]);                    \
      cT[h][(gq * 4 + 1) * XP + mcol] = (short)f2bf(CF[1]);                    \
      cT[h][(gq * 4 + 2) * XP + mcol] = (short)f2bf(CF[2]);                    \
      cT[h][(gq * 4 + 3) * XP + mcol] = (short)f2bf(CF[3]);                    \
    }

#define CP_TILE(NT2, CF)                                                       \
    {                                                                          \
      const int nt = 2 * w + NT2;                                              \
      _Pragma("unroll")                                                        \
      for (int r = 0; r < 4; ++r) {                                            \
        float v = CF[r];                                                       \
        v += __shfl_xor(v, 1); v += __shfl_xor(v, 2); v += __shfl_xor(v, 4);   \
        if ((lane & 7) == 0)                                                   \
          cp_s[h][nt * 2 + ((lane >> 3) & 1)][gq * 4 + r] = v;                 \
      }                                                                        \
    }

#define A_ROLE(LASTF)                                                          \
  {                                                                            \
    { const float* wvg = wvacc + (size_t)g * O_ * DS_;                         \
      for (int i = t; i < O_ * DS_; i += 512) {                                \
        const int o = i >> 6, k = i & 63;                                      \
        wv_s[o * WVP + k] = (short)f2bf(wvg[i]);                               \
      } }                                                                      \
    __syncthreads();                                                           \
    { const int mrow = lane & 15, gq = lane >> 4;                              \
      float c_fA[4], c_fB[4];                                                  \
      LOGIT_TILE(0, c_fA)                                                      \
      LOGIT_TILE(1, c_fB)                                                      \
      if (LASTF) { CP_TILE(0, c_fA) CP_TILE(1, c_fB) }                         \
      (void)c_fA; (void)c_fB; }                                                \
    __syncthreads();                                                           \
    { const int oc = lane & 15, gq = lane >> 4;                                \
      f32x4 y0 = {0.f,0.f,0.f,0.f}, y1 = {0.f,0.f,0.f,0.f};                    \
      _Pragma("unroll")                                                        \
      for (int ks = 0; ks < 4; ++ks) {                                         \
        short8 bfv = *(const short8*)&cT[h][oc * XP + ks * 32 + gq * 8];       \
        short8 a0 = *(const short8*)&xT[h][((2*w+0)*16 + oc) * XP + ks*32 + gq*8]; \
        short8 a1 = *(const short8*)&xT[h][((2*w+1)*16 + oc) * XP + ks*32 + gq*8]; \
        y0 = __builtin_amdgcn_mfma_f32_16x16x32_bf16(a0, bfv, y0, 0, 0, 0);    \
        y1 = __builtin_amdgcn_mfma_f32_16x16x32_bf16(a1, bfv, y1, 0, 0, 0);    \
      }                                                                        \
      _Pragma("unroll")                                                        \
      for (int r = 0; r < 4; ++r) {                                            \
        y_lds[h][oc * YLP + (2*w+0) * 16 + gq * 4 + r] = y0[r];                \
        y_lds[h][oc * YLP + (2*w+1) * 16 + gq * 4 + r] = y1[r];                \
      } }                                                                      \
    __syncthreads();                                                           \
    { float* yp = y_part + (size_t)blk_lin * 2048;                             \
      const int oo = tt >> 4, k8 = (tt & 15) * 8;                              \
      float4 q0 = *(const float4*)&y_lds[h][oo * YLP + k8];                    \
      float4 q1 = *(const float4*)&y_lds[h][oo * YLP + k8 + 4];                \
      *(float4*)&yp[tt * 8] = q0;                                              \
      *(float4*)&yp[tt * 8 + 4] = q1; }                                        \
    if (LASTF) {                                                               \
      float* rp = routed_part + (size_t)blk_lin * 768;                         \
      _Pragma("unroll")                                                        \
      for (int e = 0; e < 3; ++e) {                                            \
        const int idx = tt + 256 * e;                                          \
        const int o = idx / VC, j = idx % VC;                                  \
        float acc = 0.f;                                                       \
        _Pragma("unroll")                                                      \
        for (int n = 0; n < 16; ++n) acc += cp_s[h][n][o] * xv_s[h][n * VC + j]; \
        rp[idx] = acc;                                                         \
      } }                                                                      \
  }

#define B_ROLE(FIRSTF, LASTF)                                                  \
  {                                                                            \
    if (FIRSTF) {                                                              \
      if (t < 128) {                                                           \
        float s = 0.f;                                                         \
        _Pragma("unroll")                                                      \
        for (int ch = 0; ch < CPG; ++ch)                                       \
          s += ysum_part[(size_t)(g * CPG + ch) * 128 + t];                    \
        s *= 0.0625f;                                                          \
        yB[0][t] = s; yB[1][t] = s;                                            \
      }                                                                        \
    } else {                                                                   \
      if (t < 256) {                                                           \
        const int o2 = t >> 7, k = t & 127;                                    \
        const float* yp = y_part + (size_t)g * CPG * 2048 + (pair*2 + o2) * 128 + k; \
        float s = 0.f;                                                         \
        _Pragma("unroll")                                                      \
        for (int ch = 0; ch < CPG; ++ch) s += yp[ch * 2048];                   \
        yB[o2][k] = s;                                                         \
      }                                                                        \
    }                                                                          \
    __syncthreads();                                                           \
    float sv = 0.f;                                                            \
    if (t < 256) {                                                             \
      const int ol = t >> 7, d = t & 127, o = pair * 2 + ol;                   \
      const float* W = (d < 64) ? (Ws + (size_t)o * 4096 + d)                  \
                                : (Wv + (size_t)o * 4096 + (d - 64));          \
      const int kbase = (d < 64) ? 0 : 64;                                     \
      float s = 0.f;                                                           \
      _Pragma("unroll")                                                        \
      for (int k = 0; k < 64; ++k) s += yB[ol][kbase + k] * W[k * 64];         \
      s += bias[o * OUTD + d];                                                 \
      sv = s;                                                                  \
      float pn = s * s;                                                        \
      _Pragma("unroll")                                                        \
      for (int m = 1; m < 64; m <<= 1) pn += __shfl_xor(pn, m);                \
      if ((t & 63) == 0) pn_s[t >> 6] = pn;                                    \
    }                                                                          \
    __syncthreads();                                                           \
    if (t < 256) {                                                             \
      const int ol = t >> 7, d = t & 127, o = pair * 2 + ol;                   \
      float sn = pn_s[ol * 2] + pn_s[ol * 2 + 1];                              \
      float f = sn / ((1.f + sn) * (sqrtf(sn) + 1e-8f));                       \
      float v = f * sv;                                                        \
      if (d < 64) vB[ol][d] = v;                                               \
      if (LASTF) caps[((size_t)g * O_ + o) * OUTD + d] = v;                    \
    }                                                                          \
    __syncthreads();                                                           \
    if (!(LASTF)) {                                                            \
      if (t < 128) {                                                           \
        const int ol2 = t >> 6, k = t & 63, o2 = pair * 2 + ol2;               \
        const float* Wr = Ws + ((size_t)o2 * 64 + k) * 64;                     \
        float acc = 0.f;                                                       \
        _Pragma("unroll")                                                      \
        for (int ss = 0; ss < 64; ss += 4) {                                   \
          float4 wq = *(const float4*)(Wr + ss);                               \
          float4 vq = *(const float4*)&vB[ol2][ss];                            \
          acc += wq.x*vq.x + wq.y*vq.y + wq.z*vq.z + wq.w*vq.w;                \
        }                                                                      \
        float* wa = wvacc + ((size_t)g * O_ + o2) * 64 + k;                    \
        *wa = ((FIRSTF) ? 0.f : *wa) + acc;                                    \
      }                                                                        \
    } else {                                                                   \
      if (t < 96) {                                                            \
        const int idx = pair * 96 + t;                                         \
        const float* rp = routed_part + (size_t)g * CPG * 768 + idx;           \
        float s2 = 0.f;                                                        \
        _Pragma("unroll")                                                      \
        for (int ch = 0; ch < CPG; ++ch) s2 += rp[ch * 768];                   \
        vecs[(size_t)g * 768 + idx] = s2;                                      \
      }                                                                        \
    }                                                                          \
  }

  // ================= routing iterations =================
  B_ROLE(1, 0)                 // it0 B: v0 from colsums, wvacc '='
  graph_barrier(cnt, 16);
  A_ROLE(0)                    // it1 A: GEMM1+softmax+GEMM2 -> y_part
  graph_barrier(cnt, 24);
  B_ROLE(0, 0)                 // it1 B: v1, wvacc '+='
  graph_barrier(cnt, 32);
  A_ROLE(1)                    // it2 A: + cp + routed partials
  graph_barrier(cnt, 40);
  B_ROLE(0, 1)                 // it2 B: caps + vecs

#undef A_ROLE
#undef B_ROLE
#undef LOGIT_TILE
#undef CP_TILE
}

// ---------------------------------------------------------------------------
extern "C" void kernel_launch(void* const* d_in, const int* in_sizes, int n_in,
                              void* d_out, int out_size, void* d_ws, size_t ws_size,
                              hipStream_t stream)
{
  const float* x    = (const float*)d_in[0];
  const float* xv   = (const float*)d_in[1];
  const float* Ws   = (const float*)d_in[2];
  const float* Wv   = (const float*)d_in[3];
  const float* bias = (const float*)d_in[4];

  float* out  = (float*)d_out;
  float* caps = out;                           // (32,16,128)
  float* vecs = out + (size_t)G_ * O_ * OUTD;  // (32,16,16,3)

  // ws layout (floats): wvacc 32768 | y_part 1048576 | routed_part 393216
  //                     | ysum_part 65536 | bar (2048 u32)
  float* ws          = (float*)d_ws;
  float* wvacc       = ws;
  float* y_part      = ws + (size_t)G_ * O_ * DS_;
  float* routed_part = y_part + (size_t)G_ * CPG * 128 * 16;
  float* ysum_part   = routed_part + (size_t)G_ * CPG * 768;
  unsigned* bar      = (unsigned*)(ysum_part + (size_t)G_ * CPG * 128);

  hipMemsetAsync((void*)bar, 0, (size_t)G_ * 64 * sizeof(unsigned), stream);
  caps_mega<<<dim3(G_ * 8), dim3(512), 0, stream>>>(
      x, xv, Ws, Wv, bias, wvacc, y_part, routed_part, ysum_part,
      caps, vecs, bar);
}

// Round 6
// 49.824 us; speedup vs baseline: 8.3282x; 8.3282x over previous
//
#include <hip/hip_runtime.h>

// Fixed sizes
#define G_    32
#define O_    16
#define OUTD  128
#define DS_   64      // scalar half / SDIM
#define VC    48      // V*3
#define M_    2048    // rows per graph
#define ROWS  128     // rows per chunk
#define CPG   16      // chunks per graph
#define XP    136     // xT / cT pitch in bf16 elems (rows 16B-aligned: 272B)
#define XPD   68      // pitch in dwords
#define WVP   72      // wv_s pitch in bf16
#define YLP   132     // y_lds pitch in f32

typedef __attribute__((ext_vector_type(8))) short short8;
typedef __attribute__((ext_vector_type(4))) float f32x4;

__device__ __forceinline__ unsigned short f2bf(float f) {
  unsigned u = __float_as_uint(f);
  return (unsigned short)((u + 0x7FFFu + ((u >> 16) & 1u)) >> 16);
}
__device__ __forceinline__ float bf2f(short v) {
  return __uint_as_float(((unsigned)(unsigned short)v) << 16);
}

// Cross-block data movement: relaxed agent-scope atomics. Coherent per the
// memory model (per-access sc1 cache policy) WITHOUT any fence cacheops --
// no L2 writeback/invalidate (R5's 400us cost was __threadfence's wbl2/inv).
__device__ __forceinline__ void st_coh(float* p, float v) {
  __hip_atomic_store(p, v, __ATOMIC_RELAXED, __HIP_MEMORY_SCOPE_AGENT);
}
__device__ __forceinline__ float ld_coh(const float* p) {
  return __hip_atomic_load(p, __ATOMIC_RELAXED, __HIP_MEMORY_SCOPE_AGENT);
}

// Per-graph barrier (8 blocks/graph), fence-free:
//  1) each wave drains its own stores to the coherence point (vmcnt(0)),
//  2) block-local barrier, 3) thread 0: relaxed add + relaxed spin,
//  4) block-local barrier. Subsequent data reads are sc1 loads issued only
//  after the spin resolves -> cannot be stale. Guard bounds any pathology.
__device__ __forceinline__ void graph_barrier(unsigned* cnt, unsigned target) {
  asm volatile("s_waitcnt vmcnt(0)" ::: "memory");
  __syncthreads();
  if (threadIdx.x == 0) {
    __hip_atomic_fetch_add(cnt, 1u, __ATOMIC_RELAXED, __HIP_MEMORY_SCOPE_AGENT);
    unsigned guard = 0;
    while (__hip_atomic_load(cnt, __ATOMIC_RELAXED, __HIP_MEMORY_SCOPE_AGENT) < target) {
      __builtin_amdgcn_s_sleep(2);
      if (++guard > (1u << 20)) break;   // never trips when resident (R5 proved)
    }
  }
  __syncthreads();
}

// ---------------------------------------------------------------------------
// Single persistent kernel. Block b: g = b>>3, pair = b&7.
//  A-role: 2 chunks (pair*2 + h), h = threadIdx.x>>8; xT stays in LDS for all
//          3 routing iterations (x read from HBM exactly once).
//  B-role: 2 capsules o = pair*2 + {0,1}.
//  5 per-graph barriers replace 5 kernel boundaries.
//  Co-residency forced: 107 KB LDS -> 1 block/CU, grid 256 = #CUs.
// ---------------------------------------------------------------------------
__global__ __launch_bounds__(512) void caps_mega(
    const float* __restrict__ x, const float* __restrict__ xv,
    const float* __restrict__ Ws, const float* __restrict__ Wv,
    const float* __restrict__ bias, float* __restrict__ wvacc,
    float* __restrict__ y_part, float* __restrict__ routed_part,
    float* __restrict__ ysum_part, float* __restrict__ caps,
    float* __restrict__ vecs, unsigned* __restrict__ bar)
{
  const int b = blockIdx.x, g = b >> 3, pair = b & 7;
  const int t = threadIdx.x, h = t >> 8, tt = t & 255;
  const int lane = tt & 63, w = tt >> 6;
  const int chunk = pair * 2 + h;
  const int blk_lin = g * CPG + chunk;

  __shared__ short xT[2][128 * XP];     // 69632 B, persistent
  __shared__ short cT[2][O_ * XP];      // 8704 B
  __shared__ short wv_s[O_ * WVP];      // 2304 B
  __shared__ float y_lds[2][16 * YLP];  // 16896 B
  __shared__ float cp_s[2][16][17];     // 2176 B
  __shared__ float xv_s[2][16 * VC];    // 6144 B
  __shared__ float yB[2][128];          // 1024 B
  __shared__ float vB[2][64];           // 512 B
  __shared__ float pn_s[4];             // 16 B

  unsigned* cnt = bar + g * 64;         // 256B-strided per-graph counter

  // ================= phase 0: stage x -> xT, xv -> LDS, colsums =============
  {
    const float* xg = x + (size_t)(g * M_ + chunk * ROWS) * OUTD;
    const int rg = tt >> 2, qc = tt & 3;
    const float4* r0q = (const float4*)(xg + (size_t)(2 * rg) * OUTD + qc * 32);
    const float4* r1q = (const float4*)(xg + (size_t)(2 * rg + 1) * OUTD + qc * 32);
    float4 a0 = r0q[0], a1 = r0q[1], a2 = r0q[2], a3 = r0q[3],
           a4 = r0q[4], a5 = r0q[5], a6 = r0q[6], a7 = r0q[7];
    float4 b0 = r1q[0], b1 = r1q[1], b2 = r1q[2], b3 = r1q[3],
           b4 = r1q[4], b5 = r1q[5], b6 = r1q[6], b7 = r1q[7];
    unsigned* xTd = (unsigned*)&xT[h][0];
    const int cb = qc * 32;
#define STAGE4(S, A, B)                                                        \
    xTd[(cb + S*4 + 0) * XPD + rg] = (unsigned)f2bf(A.x) | ((unsigned)f2bf(B.x) << 16); \
    xTd[(cb + S*4 + 1) * XPD + rg] = (unsigned)f2bf(A.y) | ((unsigned)f2bf(B.y) << 16); \
    xTd[(cb + S*4 + 2) * XPD + rg] = (unsigned)f2bf(A.z) | ((unsigned)f2bf(B.z) << 16); \
    xTd[(cb + S*4 + 3) * XPD + rg] = (unsigned)f2bf(A.w) | ((unsigned)f2bf(B.w) << 16);
    STAGE4(0, a0, b0) STAGE4(1, a1, b1) STAGE4(2, a2, b2) STAGE4(3, a3, b3)
    STAGE4(4, a4, b4) STAGE4(5, a5, b5) STAGE4(6, a6, b6) STAGE4(7, a7, b7)
#undef STAGE4
  }
  {
    const float* xvg = xv + (size_t)(g * 256 + chunk * 16) * VC;
    for (int i = tt; i < 16 * VC; i += 256) xv_s[h][i] = xvg[i];
  }
  __syncthreads();
  {
    const int k = tt >> 1, half = tt & 1;
    float s = 0.f;
#pragma unroll
    for (int j = 0; j < 8; ++j) {
      short8 v = *(const short8*)&xT[h][k * XP + half * 64 + j * 8];
#pragma unroll
      for (int e = 0; e < 8; ++e) s += bf2f(v[e]);
    }
    s += __shfl_xor(s, 1);
    if (half == 0) st_coh(&ysum_part[(size_t)blk_lin * 128 + k], s);
  }
  graph_barrier(cnt, 8);

  // ---- role macros ---------------------------------------------------------
#define LOGIT_TILE(NT2, CF)                                                    \
    {                                                                          \
      const int nt = 2 * w + NT2;                                              \
      const int mcol = nt * 16 + mrow;                                         \
      f32x4 acc = {0.f, 0.f, 0.f, 0.f};                                        \
      _Pragma("unroll")                                                        \
      for (int ks = 0; ks < 2; ++ks) {                                         \
        short8 af = *(const short8*)&wv_s[mrow * WVP + ks * 32 + gq * 8];      \
        short8 bfr;                                                            \
        _Pragma("unroll")                                                      \
        for (int e = 0; e < 8; ++e)                                            \
          bfr[e] = xT[h][(ks * 32 + gq * 8 + e) * XP + mcol];                  \
        acc = __builtin_amdgcn_mfma_f32_16x16x32_bf16(af, bfr, acc, 0, 0, 0);  \
      }                                                                        \
      float mx = fmaxf(fmaxf(acc[0], acc[1]), fmaxf(acc[2], acc[3]));          \
      mx = fmaxf(mx, __shfl_xor(mx, 16));                                      \
      mx = fmaxf(mx, __shfl_xor(mx, 32));                                      \
      float e0 = __expf(acc[0] - mx), e1 = __expf(acc[1] - mx);                \
      float e2 = __expf(acc[2] - mx), e3 = __expf(acc[3] - mx);                \
      float sm = e0 + e1 + e2 + e3;                                            \
      sm += __shfl_xor(sm, 16);                                                \
      sm += __shfl_xor(sm, 32);                                                \
      float inv = 1.f / sm;                                                    \
      CF[0] = e0 * inv; CF[1] = e1 * inv; CF[2] = e2 * inv; CF[3] = e3 * inv;  \
      cT[h][(gq * 4 + 0) * XP + mcol] = (short)f2bf(CF[0]);                    \
      cT[h][(gq * 4 + 1) * XP + mcol] = (short)f2bf(CF[1]);                    \
      cT[h][(gq * 4 + 2) * XP + mcol] = (short)f2bf(CF[2]);                    \
      cT[h][(gq * 4 + 3) * XP + mcol] = (short)f2bf(CF[3]);                    \
    }

#define CP_TILE(NT2, CF)                                                       \
    {                                                                          \
      const int nt = 2 * w + NT2;                                              \
      _Pragma("unroll")                                                        \
      for (int r = 0; r < 4; ++r) {                                            \
        float v = CF[r];                                                       \
        v += __shfl_xor(v, 1); v += __shfl_xor(v, 2); v += __shfl_xor(v, 4);   \
        if ((lane & 7) == 0)                                                   \
          cp_s[h][nt * 2 + ((lane >> 3) & 1)][gq * 4 + r] = v;                 \
      }                                                                        \
    }

#define A_ROLE(LASTF)                                                          \
  {                                                                            \
    { const float* wvg = wvacc + (size_t)g * O_ * DS_;                         \
      for (int i = t; i < O_ * DS_; i += 512) {                                \
        const int o = i >> 6, k = i & 63;                                      \
        wv_s[o * WVP + k] = (short)f2bf(ld_coh(&wvg[i]));                      \
      } }                                                                      \
    __syncthreads();                                                           \
    { const int mrow = lane & 15, gq = lane >> 4;                              \
      float c_fA[4], c_fB[4];                                                  \
      LOGIT_TILE(0, c_fA)                                                      \
      LOGIT_TILE(1, c_fB)                                                      \
      if (LASTF) { CP_TILE(0, c_fA) CP_TILE(1, c_fB) }                         \
      (void)c_fA; (void)c_fB; }                                                \
    __syncthreads();                                                           \
    { const int oc = lane & 15, gq = lane >> 4;                                \
      f32x4 y0 = {0.f,0.f,0.f,0.f}, y1 = {0.f,0.f,0.f,0.f};                    \
      _Pragma("unroll")                                                        \
      for (int ks = 0; ks < 4; ++ks) {                                         \
        short8 bfv = *(const short8*)&cT[h][oc * XP + ks * 32 + gq * 8];       \
        short8 a0 = *(const short8*)&xT[h][((2*w+0)*16 + oc) * XP + ks*32 + gq*8]; \
        short8 a1 = *(const short8*)&xT[h][((2*w+1)*16 + oc) * XP + ks*32 + gq*8]; \
        y0 = __builtin_amdgcn_mfma_f32_16x16x32_bf16(a0, bfv, y0, 0, 0, 0);    \
        y1 = __builtin_amdgcn_mfma_f32_16x16x32_bf16(a1, bfv, y1, 0, 0, 0);    \
      }                                                                        \
      _Pragma("unroll")                                                        \
      for (int r = 0; r < 4; ++r) {                                            \
        y_lds[h][oc * YLP + (2*w+0) * 16 + gq * 4 + r] = y0[r];                \
        y_lds[h][oc * YLP + (2*w+1) * 16 + gq * 4 + r] = y1[r];                \
      } }                                                                      \
    __syncthreads();                                                           \
    { float* yp = y_part + (size_t)blk_lin * 2048;                             \
      const int oo = tt >> 4, k8 = (tt & 15) * 8;                              \
      _Pragma("unroll")                                                        \
      for (int e = 0; e < 8; ++e)                                              \
        st_coh(&yp[tt * 8 + e], y_lds[h][oo * YLP + k8 + e]); }                \
    if (LASTF) {                                                               \
      float* rp = routed_part + (size_t)blk_lin * 768;                         \
      _Pragma("unroll")                                                        \
      for (int e = 0; e < 3; ++e) {                                            \
        const int idx = tt + 256 * e;                                          \
        const int o = idx / VC, j = idx % VC;                                  \
        float acc = 0.f;                                                       \
        _Pragma("unroll")                                                      \
        for (int n = 0; n < 16; ++n) acc += cp_s[h][n][o] * xv_s[h][n * VC + j]; \
        st_coh(&rp[idx], acc);                                                 \
      } }                                                                      \
  }

#define B_ROLE(FIRSTF, LASTF)                                                  \
  {                                                                            \
    if (FIRSTF) {                                                              \
      if (t < 128) {                                                           \
        float s = 0.f;                                                         \
        _Pragma("unroll")                                                      \
        for (int ch = 0; ch < CPG; ++ch)                                       \
          s += ld_coh(&ysum_part[(size_t)(g * CPG + ch) * 128 + t]);           \
        s *= 0.0625f;                                                          \
        yB[0][t] = s; yB[1][t] = s;                                            \
      }                                                                        \
    } else {                                                                   \
      if (t < 256) {                                                           \
        const int o2 = t >> 7, k = t & 127;                                    \
        const float* yp = y_part + (size_t)g * CPG * 2048 + (pair*2 + o2) * 128 + k; \
        float s = 0.f;                                                         \
        _Pragma("unroll")                                                      \
        for (int ch = 0; ch < CPG; ++ch) s += ld_coh(&yp[ch * 2048]);          \
        yB[o2][k] = s;                                                         \
      }                                                                        \
    }                                                                          \
    __syncthreads();                                                           \
    float sv = 0.f;                                                            \
    if (t < 256) {                                                             \
      const int ol = t >> 7, d = t & 127, o = pair * 2 + ol;                   \
      const float* W = (d < 64) ? (Ws + (size_t)o * 4096 + d)                  \
                                : (Wv + (size_t)o * 4096 + (d - 64));          \
      const int kbase = (d < 64) ? 0 : 64;                                     \
      float s = 0.f;                                                           \
      _Pragma("unroll")                                                        \
      for (int k = 0; k < 64; ++k) s += yB[ol][kbase + k] * W[k * 64];         \
      s += bias[o * OUTD + d];                                                 \
      sv = s;                                                                  \
      float pn = s * s;                                                        \
      _Pragma("unroll")                                                        \
      for (int m = 1; m < 64; m <<= 1) pn += __shfl_xor(pn, m);                \
      if ((t & 63) == 0) pn_s[t >> 6] = pn;                                    \
    }                                                                          \
    __syncthreads();                                                           \
    if (t < 256) {                                                             \
      const int ol = t >> 7, d = t & 127, o = pair * 2 + ol;                   \
      float sn = pn_s[ol * 2] + pn_s[ol * 2 + 1];                              \
      float f = sn / ((1.f + sn) * (sqrtf(sn) + 1e-8f));                       \
      float v = f * sv;                                                        \
      if (d < 64) vB[ol][d] = v;                                               \
      if (LASTF) caps[((size_t)g * O_ + o) * OUTD + d] = v;                    \
    }                                                                          \
    __syncthreads();                                                           \
    if (!(LASTF)) {                                                            \
      if (t < 128) {                                                           \
        const int ol2 = t >> 6, k = t & 63, o2 = pair * 2 + ol2;               \
        const float* Wr = Ws + ((size_t)o2 * 64 + k) * 64;                     \
        float acc = 0.f;                                                       \
        _Pragma("unroll")                                                      \
        for (int ss = 0; ss < 64; ss += 4) {                                   \
          float4 wq = *(const float4*)(Wr + ss);                               \
          float4 vq = *(const float4*)&vB[ol2][ss];                            \
          acc += wq.x*vq.x + wq.y*vq.y + wq.z*vq.z + wq.w*vq.w;                \
        }                                                                      \
        float* wa = wvacc + ((size_t)g * O_ + o2) * 64 + k;                    \
        float old = (FIRSTF) ? 0.f : ld_coh(wa);                               \
        st_coh(wa, old + acc);                                                 \
      }                                                                        \
    } else {                                                                   \
      if (t < 96) {                                                            \
        const int idx = pair * 96 + t;                                         \
        const float* rp = routed_part + (size_t)g * CPG * 768 + idx;           \
        float s2 = 0.f;                                                        \
        _Pragma("unroll")                                                      \
        for (int ch = 0; ch < CPG; ++ch) s2 += ld_coh(&rp[ch * 768]);          \
        vecs[(size_t)g * 768 + idx] = s2;                                      \
      }                                                                        \
    }                                                                          \
  }

  // ================= routing iterations =================
  B_ROLE(1, 0)                 // it0 B: v0 from colsums, wvacc '='
  graph_barrier(cnt, 16);
  A_ROLE(0)                    // it1 A: GEMM1+softmax+GEMM2 -> y_part
  graph_barrier(cnt, 24);
  B_ROLE(0, 0)                 // it1 B: v1, wvacc '+='
  graph_barrier(cnt, 32);
  A_ROLE(1)                    // it2 A: + cp + routed partials
  graph_barrier(cnt, 40);
  B_ROLE(0, 1)                 // it2 B: caps + vecs

#undef A_ROLE
#undef B_ROLE
#undef LOGIT_TILE
#undef CP_TILE
}

// ---------------------------------------------------------------------------
extern "C" void kernel_launch(void* const* d_in, const int* in_sizes, int n_in,
                              void* d_out, int out_size, void* d_ws, size_t ws_size,
                              hipStream_t stream)
{
  const float* x    = (const float*)d_in[0];
  const float* xv   = (const float*)d_in[1];
  const float* Ws   = (const float*)d_in[2];
  const float* Wv   = (const float*)d_in[3];
  const float* bias = (const float*)d_in[4];

  float* out  = (float*)d_out;
  float* caps = out;                           // (32,16,128)
  float* vecs = out + (size_t)G_ * O_ * OUTD;  // (32,16,16,3)

  // ws layout (floats): wvacc 32768 | y_part 1048576 | routed_part 393216
  //                     | ysum_part 65536 | bar (2048 u32)
  float* ws          = (float*)d_ws;
  float* wvacc       = ws;
  float* y_part      = ws + (size_t)G_ * O_ * DS_;
  float* routed_part = y_part + (size_t)G_ * CPG * 128 * 16;
  float* ysum_part   = routed_part + (size_t)G_ * CPG * 768;
  unsigned* bar      = (unsigned*)(ysum_part + (size_t)G_ * CPG * 128);

  hipMemsetAsync((void*)bar, 0, (size_t)G_ * 64 * sizeof(unsigned), stream);
  caps_mega<<<dim3(G_ * 8), dim3(512), 0, stream>>>(
      x, xv, Ws, Wv, bias, wvacc, y_part, routed_part, ysum_part,
      caps, vecs, bar);
}

// Round 7
// 43.383 us; speedup vs baseline: 9.5646x; 1.1485x over previous
//
#include <hip/hip_runtime.h>

// Fixed sizes
#define G_    32
#define O_    16
#define OUTD  128
#define DS_   64      // scalar half / SDIM
#define VC    48      // V*3
#define M_    2048    // rows per graph
#define ROWS  128     // rows per chunk
#define CPG   16      // chunks per graph
#define XP    136     // xT / cT pitch in bf16 elems (rows 16B-aligned: 272B)
#define XPD   68      // pitch in dwords
#define WVP   72      // wv_s pitch in bf16
#define YLP   132     // y_lds pitch in f32

typedef __attribute__((ext_vector_type(8))) short short8;
typedef __attribute__((ext_vector_type(4))) float f32x4;
typedef unsigned long long u64_t;

__device__ __forceinline__ unsigned short f2bf(float f) {
  unsigned u = __float_as_uint(f);
  return (unsigned short)((u + 0x7FFFu + ((u >> 16) & 1u)) >> 16);
}
__device__ __forceinline__ float bf2f(short v) {
  return __uint_as_float(((unsigned)(unsigned short)v) << 16);
}

// 8B coherent I/O: relaxed agent-scope atomics on u64 (native, lock-free,
// compiler-tracked waitcnts). Same proven coherence model as R6, half the
// instruction count and proper 8B write-combining at the coherence point.
__device__ __forceinline__ void st8f(float* p, float a, float b) {
  union { float f[2]; u64_t u; } x; x.f[0] = a; x.f[1] = b;
  __hip_atomic_store((u64_t*)p, x.u, __ATOMIC_RELAXED, __HIP_MEMORY_SCOPE_AGENT);
}
__device__ __forceinline__ void ld8f(const float* p, float& a, float& b) {
  union { float f[2]; u64_t u; } x;
  x.u = __hip_atomic_load((const u64_t*)p, __ATOMIC_RELAXED, __HIP_MEMORY_SCOPE_AGENT);
  a = x.f[0]; b = x.f[1];
}

// Per-graph barrier (8 blocks/graph), fence-free (proven in R6).
__device__ __forceinline__ void graph_barrier(unsigned* cnt, unsigned target) {
  asm volatile("s_waitcnt vmcnt(0)" ::: "memory");
  __syncthreads();
  if (threadIdx.x == 0) {
    __hip_atomic_fetch_add(cnt, 1u, __ATOMIC_RELAXED, __HIP_MEMORY_SCOPE_AGENT);
    unsigned guard = 0;
    while (__hip_atomic_load(cnt, __ATOMIC_RELAXED, __HIP_MEMORY_SCOPE_AGENT) < target) {
      __builtin_amdgcn_s_sleep(1);
      if (++guard > (1u << 20)) break;
    }
  }
  __syncthreads();
}

// ---------------------------------------------------------------------------
// Single persistent kernel. Block b: g = b>>3, pair = b&7.
//  A-role: 2 chunks (pair*2 + h), h = t>>8; xT persistent in LDS.
//  B-role: 2 capsules o = pair*2 + {0,1}; wvacc f32 accumulator lives in
//          block-local LDS (only this block RMWs it); the cross-block copy
//          is bf16 (2 KB/graph), pre-converted so A skips f2bf entirely.
//  Co-residency forced: ~105 KB LDS -> 1 block/CU, grid 256 = #CUs.
// ---------------------------------------------------------------------------
__global__ __launch_bounds__(512) void caps_mega(
    const float* __restrict__ x, const float* __restrict__ xv,
    const float* __restrict__ Ws, const float* __restrict__ Wv,
    const float* __restrict__ bias, short* __restrict__ wvacc_bf,
    float* __restrict__ y_part, float* __restrict__ routed_part,
    float* __restrict__ ysum_part, float* __restrict__ caps,
    float* __restrict__ vecs, unsigned* __restrict__ bar)
{
  const int b = blockIdx.x, g = b >> 3, pair = b & 7;
  const int t = threadIdx.x, h = t >> 8, tt = t & 255;
  const int lane = tt & 63, w = tt >> 6;
  const int chunk = pair * 2 + h;
  const int blk_lin = g * CPG + chunk;

  __shared__ short xT[2][128 * XP];     // 69632 B, persistent
  __shared__ short cT[2][O_ * XP];      // 8704 B
  __shared__ short wv_s[O_ * WVP];      // 2304 B
  __shared__ float y_lds[2][16 * YLP];  // 16896 B
  __shared__ float cp_s[2][16][17];     // 2176 B
  __shared__ float xv_s[2][16 * VC];    // 6144 B
  __shared__ float yB[2][128];          // 1024 B
  __shared__ float vB[2][64];           // 512 B
  __shared__ float pn_s[4];             // 16 B
  __shared__ float wv_acc_s[2][64];     // 512 B, persistent B-role accumulator

  unsigned* cnt = bar + g * 64;         // 256B-strided per-graph counter

  // ================= phase 0: stage x -> xT, xv -> LDS, colsums =============
  {
    const float* xg = x + (size_t)(g * M_ + chunk * ROWS) * OUTD;
    const int rg = tt >> 2, qc = tt & 3;
    const float4* r0q = (const float4*)(xg + (size_t)(2 * rg) * OUTD + qc * 32);
    const float4* r1q = (const float4*)(xg + (size_t)(2 * rg + 1) * OUTD + qc * 32);
    float4 a0 = r0q[0], a1 = r0q[1], a2 = r0q[2], a3 = r0q[3],
           a4 = r0q[4], a5 = r0q[5], a6 = r0q[6], a7 = r0q[7];
    float4 b0 = r1q[0], b1 = r1q[1], b2 = r1q[2], b3 = r1q[3],
           b4 = r1q[4], b5 = r1q[5], b6 = r1q[6], b7 = r1q[7];
    unsigned* xTd = (unsigned*)&xT[h][0];
    const int cb = qc * 32;
#define STAGE4(S, A, B)                                                        \
    xTd[(cb + S*4 + 0) * XPD + rg] = (unsigned)f2bf(A.x) | ((unsigned)f2bf(B.x) << 16); \
    xTd[(cb + S*4 + 1) * XPD + rg] = (unsigned)f2bf(A.y) | ((unsigned)f2bf(B.y) << 16); \
    xTd[(cb + S*4 + 2) * XPD + rg] = (unsigned)f2bf(A.z) | ((unsigned)f2bf(B.z) << 16); \
    xTd[(cb + S*4 + 3) * XPD + rg] = (unsigned)f2bf(A.w) | ((unsigned)f2bf(B.w) << 16);
    STAGE4(0, a0, b0) STAGE4(1, a1, b1) STAGE4(2, a2, b2) STAGE4(3, a3, b3)
    STAGE4(4, a4, b4) STAGE4(5, a5, b5) STAGE4(6, a6, b6) STAGE4(7, a7, b7)
#undef STAGE4
  }
  {
    const float* xvg = xv + (size_t)(g * 256 + chunk * 16) * VC;
    for (int i = tt; i < 16 * VC; i += 256) xv_s[h][i] = xvg[i];
  }
  __syncthreads();
  {
    const int k = tt >> 1, half = tt & 1;
    float s = 0.f;
#pragma unroll
    for (int j = 0; j < 8; ++j) {
      short8 v = *(const short8*)&xT[h][k * XP + half * 64 + j * 8];
#pragma unroll
      for (int e = 0; e < 8; ++e) s += bf2f(v[e]);
    }
    s += __shfl_xor(s, 1);                  // combine halves -> full colsum(k)
    float s1 = __shfl_xor(s, 2);            // neighbor's colsum(k+1)
    if ((tt & 3) == 0) st8f(&ysum_part[(size_t)blk_lin * 128 + k], s, s1);
  }
  graph_barrier(cnt, 8);

  // ---- role macros ---------------------------------------------------------
#define LOGIT_TILE(NT2, CF)                                                    \
    {                                                                          \
      const int nt = 2 * w + NT2;                                              \
      const int mcol = nt * 16 + mrow;                                         \
      f32x4 acc = {0.f, 0.f, 0.f, 0.f};                                        \
      _Pragma("unroll")                                                        \
      for (int ks = 0; ks < 2; ++ks) {                                         \
        short8 af = *(const short8*)&wv_s[mrow * WVP + ks * 32 + gq * 8];      \
        short8 bfr;                                                            \
        _Pragma("unroll")                                                      \
        for (int e = 0; e < 8; ++e)                                            \
          bfr[e] = xT[h][(ks * 32 + gq * 8 + e) * XP + mcol];                  \
        acc = __builtin_amdgcn_mfma_f32_16x16x32_bf16(af, bfr, acc, 0, 0, 0);  \
      }                                                                        \
      float mx = fmaxf(fmaxf(acc[0], acc[1]), fmaxf(acc[2], acc[3]));          \
      mx = fmaxf(mx, __shfl_xor(mx, 16));                                      \
      mx = fmaxf(mx, __shfl_xor(mx, 32));                                      \
      float e0 = __expf(acc[0] - mx), e1 = __expf(acc[1] - mx);                \
      float e2 = __expf(acc[2] - mx), e3 = __expf(acc[3] - mx);                \
      float sm = e0 + e1 + e2 + e3;                                            \
      sm += __shfl_xor(sm, 16);                                                \
      sm += __shfl_xor(sm, 32);                                                \
      float inv = 1.f / sm;                                                    \
      CF[0] = e0 * inv; CF[1] = e1 * inv; CF[2] = e2 * inv; CF[3] = e3 * inv;  \
      cT[h][(gq * 4 + 0) * XP + mcol] = (short)f2bf(CF[0]);                    \
      cT[h][(gq * 4 + 1) * XP + mcol] = (short)f2bf(CF[1]);                    \
      cT[h][(gq * 4 + 2) * XP + mcol] = (short)f2bf(CF[2]);                    \
      cT[h][(gq * 4 + 3) * XP + mcol] = (short)f2bf(CF[3]);                    \
    }

#define CP_TILE(NT2, CF)                                                       \
    {                                                                          \
      const int nt = 2 * w + NT2;                                              \
      _Pragma("unroll")                                                        \
      for (int r = 0; r < 4; ++r) {                                            \
        float v = CF[r];                                                       \
        v += __shfl_xor(v, 1); v += __shfl_xor(v, 2); v += __shfl_xor(v, 4);   \
        if ((lane & 7) == 0)                                                   \
          cp_s[h][nt * 2 + ((lane >> 3) & 1)][gq * 4 + r] = v;                 \
      }                                                                        \
    }

#define A_ROLE(LASTF)                                                          \
  {                                                                            \
    if (t < 256) {                                                             \
      u64_t v4 = __hip_atomic_load(                                            \
          (const u64_t*)&wvacc_bf[(size_t)g * 1024 + t * 4],                   \
          __ATOMIC_RELAXED, __HIP_MEMORY_SCOPE_AGENT);                         \
      const int o = (t * 4) >> 6, k = (t * 4) & 63;                            \
      wv_s[o * WVP + k + 0] = (short)(v4 & 0xFFFF);                            \
      wv_s[o * WVP + k + 1] = (short)((v4 >> 16) & 0xFFFF);                    \
      wv_s[o * WVP + k + 2] = (short)((v4 >> 32) & 0xFFFF);                    \
      wv_s[o * WVP + k + 3] = (short)((v4 >> 48) & 0xFFFF);                    \
    }                                                                          \
    __syncthreads();                                                           \
    { const int mrow = lane & 15, gq = lane >> 4;                              \
      float c_fA[4], c_fB[4];                                                  \
      LOGIT_TILE(0, c_fA)                                                      \
      LOGIT_TILE(1, c_fB)                                                      \
      if (LASTF) { CP_TILE(0, c_fA) CP_TILE(1, c_fB) }                         \
      (void)c_fA; (void)c_fB; }                                                \
    __syncthreads();                                                           \
    { const int oc = lane & 15, gq = lane >> 4;                                \
      f32x4 y0 = {0.f,0.f,0.f,0.f}, y1 = {0.f,0.f,0.f,0.f};                    \
      _Pragma("unroll")                                                        \
      for (int ks = 0; ks < 4; ++ks) {                                         \
        short8 bfv = *(const short8*)&cT[h][oc * XP + ks * 32 + gq * 8];       \
        short8 a0 = *(const short8*)&xT[h][((2*w+0)*16 + oc) * XP + ks*32 + gq*8]; \
        short8 a1 = *(const short8*)&xT[h][((2*w+1)*16 + oc) * XP + ks*32 + gq*8]; \
        y0 = __builtin_amdgcn_mfma_f32_16x16x32_bf16(a0, bfv, y0, 0, 0, 0);    \
        y1 = __builtin_amdgcn_mfma_f32_16x16x32_bf16(a1, bfv, y1, 0, 0, 0);    \
      }                                                                        \
      _Pragma("unroll")                                                        \
      for (int r = 0; r < 4; ++r) {                                            \
        y_lds[h][oc * YLP + (2*w+0) * 16 + gq * 4 + r] = y0[r];                \
        y_lds[h][oc * YLP + (2*w+1) * 16 + gq * 4 + r] = y1[r];                \
      } }                                                                      \
    __syncthreads();                                                           \
    { float* yp = y_part + (size_t)blk_lin * 2048;                             \
      const int oo = tt >> 4, k8 = (tt & 15) * 8;                              \
      const float* sp = &y_lds[h][oo * YLP + k8];                              \
      _Pragma("unroll")                                                        \
      for (int e = 0; e < 4; ++e)                                              \
        st8f(&yp[tt * 8 + 2*e], sp[2*e], sp[2*e + 1]); }                       \
    if (LASTF) {                                                               \
      float* rp = routed_part + (size_t)blk_lin * 768;                         \
      _Pragma("unroll")                                                        \
      for (int e = 0; e < 2; ++e) {                                            \
        const int q = tt + 256 * e;                                            \
        if (q < 384) {                                                         \
          const int idx0 = 2 * q;                                              \
          const int o = idx0 / VC, j = idx0 - o * VC;                          \
          float a0 = 0.f, a1 = 0.f;                                            \
          _Pragma("unroll")                                                    \
          for (int n = 0; n < 16; ++n) {                                       \
            a0 += cp_s[h][n][o] * xv_s[h][n * VC + j];                         \
            a1 += cp_s[h][n][o] * xv_s[h][n * VC + j + 1];                     \
          }                                                                    \
          st8f(&rp[idx0], a0, a1);                                             \
        } } }                                                                  \
  }

#define B_ROLE(FIRSTF, LASTF)                                                  \
  {                                                                            \
    if (FIRSTF) {                                                              \
      if (t < 64) {                                                            \
        float s0 = 0.f, s1 = 0.f;                                              \
        _Pragma("unroll")                                                      \
        for (int ch = 0; ch < CPG; ++ch) {                                     \
          float a, bb;                                                         \
          ld8f(&ysum_part[(size_t)(g * CPG + ch) * 128 + 2 * t], a, bb);       \
          s0 += a; s1 += bb;                                                   \
        }                                                                      \
        s0 *= 0.0625f; s1 *= 0.0625f;                                          \
        yB[0][2*t] = s0; yB[0][2*t+1] = s1;                                    \
        yB[1][2*t] = s0; yB[1][2*t+1] = s1;                                    \
      }                                                                        \
    } else {                                                                   \
      if (t < 128) {                                                           \
        const int o2 = t >> 6, kp = t & 63;                                    \
        const float* yp = y_part + (size_t)g * CPG * 2048 + (pair*2 + o2) * 128 + kp * 2; \
        float s0 = 0.f, s1 = 0.f;                                              \
        _Pragma("unroll")                                                      \
        for (int ch = 0; ch < CPG; ++ch) {                                     \
          float a, bb; ld8f(&yp[ch * 2048], a, bb);                            \
          s0 += a; s1 += bb;                                                   \
        }                                                                      \
        yB[o2][kp*2] = s0; yB[o2][kp*2+1] = s1;                                \
      }                                                                        \
    }                                                                          \
    __syncthreads();                                                           \
    float sv = 0.f;                                                            \
    if (t < 256) {                                                             \
      const int ol = t >> 7, d = t & 127, o = pair * 2 + ol;                   \
      const float* W = (d < 64) ? (Ws + (size_t)o * 4096 + d)                  \
                                : (Wv + (size_t)o * 4096 + (d - 64));          \
      const int kbase = (d < 64) ? 0 : 64;                                     \
      float s = 0.f;                                                           \
      _Pragma("unroll")                                                        \
      for (int k = 0; k < 64; ++k) s += yB[ol][kbase + k] * W[k * 64];         \
      s += bias[o * OUTD + d];                                                 \
      sv = s;                                                                  \
      float pn = s * s;                                                        \
      _Pragma("unroll")                                                        \
      for (int m = 1; m < 64; m <<= 1) pn += __shfl_xor(pn, m);                \
      if ((t & 63) == 0) pn_s[t >> 6] = pn;                                    \
    }                                                                          \
    __syncthreads();                                                           \
    if (t < 256) {                                                             \
      const int ol = t >> 7, d = t & 127, o = pair * 2 + ol;                   \
      float sn = pn_s[ol * 2] + pn_s[ol * 2 + 1];                              \
      float f = sn / ((1.f + sn) * (sqrtf(sn) + 1e-8f));                       \
      float v = f * sv;                                                        \
      if (d < 64) vB[ol][d] = v;                                               \
      if (LASTF) caps[((size_t)g * O_ + o) * OUTD + d] = v;                    \
    }                                                                          \
    __syncthreads();                                                           \
    if (!(LASTF)) {                                                            \
      if (t < 128) {                                                           \
        const int ol2 = t >> 6, k = t & 63, o2 = pair * 2 + ol2;               \
        const float* Wr = Ws + ((size_t)o2 * 64 + k) * 64;                     \
        float acc = 0.f;                                                       \
        _Pragma("unroll")                                                      \
        for (int ss = 0; ss < 64; ss += 4) {                                   \
          float4 wq = *(const float4*)(Wr + ss);                               \
          float4 vq = *(const float4*)&vB[ol2][ss];                            \
          acc += wq.x*vq.x + wq.y*vq.y + wq.z*vq.z + wq.w*vq.w;                \
        }                                                                      \
        wv_acc_s[ol2][k] = ((FIRSTF) ? 0.f : wv_acc_s[ol2][k]) + acc;          \
      }                                                                        \
      __syncthreads();                                                         \
      if (t < 32) {                                                            \
        const int ol2 = t >> 4, k = (t & 15) * 4;                              \
        u64_t v4 =  (u64_t)(unsigned short)f2bf(wv_acc_s[ol2][k + 0])          \
                 | ((u64_t)(unsigned short)f2bf(wv_acc_s[ol2][k + 1]) << 16)   \
                 | ((u64_t)(unsigned short)f2bf(wv_acc_s[ol2][k + 2]) << 32)   \
                 | ((u64_t)(unsigned short)f2bf(wv_acc_s[ol2][k + 3]) << 48);  \
        __hip_atomic_store(                                                    \
            (u64_t*)&wvacc_bf[(size_t)g * 1024 + (pair * 2 + ol2) * 64 + k],   \
            v4, __ATOMIC_RELAXED, __HIP_MEMORY_SCOPE_AGENT);                   \
      }                                                                        \
    } else {                                                                   \
      if (t < 48) {                                                            \
        const int idx = pair * 96 + 2 * t;                                     \
        const float* rp = routed_part + (size_t)g * CPG * 768 + idx;           \
        float s0 = 0.f, s1 = 0.f;                                              \
        _Pragma("unroll")                                                      \
        for (int ch = 0; ch < CPG; ++ch) {                                     \
          float a, bb; ld8f(&rp[ch * 768], a, bb);                             \
          s0 += a; s1 += bb;                                                   \
        }                                                                      \
        vecs[(size_t)g * 768 + idx] = s0;                                      \
        vecs[(size_t)g * 768 + idx + 1] = s1;                                  \
      }                                                                        \
    }                                                                          \
  }

  // ================= routing iterations =================
  B_ROLE(1, 0)                 // it0 B: v0 from colsums, wvacc '='
  graph_barrier(cnt, 16);
  A_ROLE(0)                    // it1 A: GEMM1+softmax+GEMM2 -> y_part
  graph_barrier(cnt, 24);
  B_ROLE(0, 0)                 // it1 B: v1, wvacc '+='
  graph_barrier(cnt, 32);
  A_ROLE(1)                    // it2 A: + cp + routed partials
  graph_barrier(cnt, 40);
  B_ROLE(0, 1)                 // it2 B: caps + vecs

#undef A_ROLE
#undef B_ROLE
#undef LOGIT_TILE
#undef CP_TILE
}

// ---------------------------------------------------------------------------
extern "C" void kernel_launch(void* const* d_in, const int* in_sizes, int n_in,
                              void* d_out, int out_size, void* d_ws, size_t ws_size,
                              hipStream_t stream)
{
  const float* x    = (const float*)d_in[0];
  const float* xv   = (const float*)d_in[1];
  const float* Ws   = (const float*)d_in[2];
  const float* Wv   = (const float*)d_in[3];
  const float* bias = (const float*)d_in[4];

  float* out  = (float*)d_out;
  float* caps = out;                           // (32,16,128)
  float* vecs = out + (size_t)G_ * O_ * OUTD;  // (32,16,16,3)

  // ws layout: bar (2048 u32) | ysum 65536 f | y_part 1048576 f
  //            | routed 393216 f | wvacc_bf 32768 bf16
  float* ws          = (float*)d_ws;
  unsigned* bar      = (unsigned*)ws;
  float* ysum_part   = ws + 4096;
  float* y_part      = ysum_part + (size_t)G_ * CPG * 128;
  float* routed_part = y_part + (size_t)G_ * CPG * 2048;
  short* wvacc_bf    = (short*)(routed_part + (size_t)G_ * CPG * 768);

  hipMemsetAsync((void*)bar, 0, (size_t)G_ * 64 * sizeof(unsigned), stream);
  caps_mega<<<dim3(G_ * 8), dim3(512), 0, stream>>>(
      x, xv, Ws, Wv, bias, wvacc_bf, y_part, routed_part, ysum_part,
      caps, vecs, bar);
}